// Round 3
// baseline (205.840 us; speedup 1.0000x reference)
//
#include <hip/hip_runtime.h>

// Dilate = 5x5 per-channel max filter, SAME padding, (64,384,384,3) f32.
// v4: streaming-wave restructure.
//   v2/v3 post-mortem: one-shot {load 16, compute, store 12} waves convoy -
//   synchronized load burst, then memory-silent compute/store, short wave
//   lifetime. VGPR_Count=52 across launch_bounds AND sched_barrier attempts
//   proves the 16-deep per-wave window can't be forced; measured 29% HBM
//   duty cycle == burst duty cycle. fillBuffer (6.4 TB/s @ 9% occ) and
//   grid-stride copy (6.3 TB/s) show the winning shape: long-lived waves
//   issuing memory CONTINUOUSLY.
//   This version: each wave streams 24 output rows of a column strip with
//   a rolling 5-row window and explicit prefetch distance PF=8:
//     per iter: load row i+PF | vertical 5-max | 12-shuffle h-max | nt-store.
//   Vertical SAME padding via address clamp ONLY (max with a duplicated
//   in-window row is identity) - all row masking deleted.
//   grid = 64 img x 5 strips x 4 chunks = 1280 blocks (5/CU exact,
//   launch_bounds(256,5) -> <=102 VGPR, 20 waves/CU); XCD swizzle kept
//   (FETCH 70->55 MB verified in v2).

#define Bn 64
#define H 384
#define ROWF 1152            // floats per image row (384*3)
#define ROWBYTES (ROWF * 4)
#define WF4 288              // float4s per row
#define RB 24                // output rows per wave
#define NLOAD (RB + 4)       // 28 input rows per wave (incl halo)
#define PF 8                 // prefetch distance (loads issued ahead)
#define CHUNKS 4             // 4 waves/block * 24 rows * 4 chunks = 384
#define STRIPS 5             // 5 * 60 = 300 >= 288 output f4 cols
#define SOUT 60
#define NBLK (Bn * STRIPS * CHUNKS)   // 1280 (divisible by 8)
#define NEGINF (-3.402823466e+38f)

typedef float f32x4 __attribute__((ext_vector_type(4)));

__device__ __forceinline__ float4 max4(float4 a, float4 b) {
  return make_float4(fmaxf(a.x, b.x), fmaxf(a.y, b.y),
                     fmaxf(a.z, b.z), fmaxf(a.w, b.w));
}
__device__ __forceinline__ float4 shflup4(float4 v, int d) {
  return make_float4(__shfl_up(v.x, d), __shfl_up(v.y, d),
                     __shfl_up(v.z, d), __shfl_up(v.w, d));
}
__device__ __forceinline__ float4 shfldn4(float4 v, int d) {
  return make_float4(__shfl_down(v.x, d), __shfl_down(v.y, d),
                     __shfl_down(v.z, d), __shfl_down(v.w, d));
}

__global__ __launch_bounds__(256, 5) void dilate5_kernel(
    const float* __restrict__ in, float* __restrict__ out) {
  const int wv = threadIdx.x >> 6;
  const int lane = threadIdx.x & 63;

  // XCD-aware swizzle: XCD x owns 8 consecutive images -> halo re-reads
  // hit its private L2 (verified: FETCH 70->55 MB).
  const int orig = blockIdx.x;
  int t = (orig & 7) * (NBLK / 8) + (orig >> 3);
  const int strip = t % STRIPS; t /= STRIPS;
  const int chunk = t % CHUNKS; t /= CHUNKS;
  const int b = t;

  const int r0 = (chunk * 4 + wv) * RB;             // 0..360 step 24
  const int col = strip * SOUT - 2 + lane;          // owned f4 col (may be OOB)
  const bool cvalid = (col >= 0) && (col < WF4);
  const int ccl = col < 0 ? 0 : (col > WF4 - 1 ? WF4 - 1 : col);
  const size_t coff = (size_t)ccl * 16;
  const bool willstore = (lane >= 2) && (lane < 62) && (col < WF4);

  const float4 ninf = make_float4(NEGINF, NEGINF, NEGINF, NEGINF);
  const char* __restrict__ imgb = (const char*)in + (size_t)b * H * ROWBYTES;
  char* __restrict__ outb = (char*)out + (size_t)b * H * ROWBYTES;

  // Address-clamped row load: vertical SAME padding falls out of the clamp
  // (max over a duplicated in-window row == max over the valid rows).
  auto loadrow = [&](int gh) -> float4 {
    int ghc = gh < 0 ? 0 : (gh > H - 1 ? H - 1 : gh);
    return *reinterpret_cast<const float4*>(imgb + (size_t)ghc * ROWBYTES + coff);
  };

  // ---- Prologue: fill rolling window + prefetch pipeline (PF loads) ----
  float4 raw[NLOAD];
#pragma unroll
  for (int j = 0; j < PF; ++j) raw[j] = loadrow(r0 - 2 + j);

  // ---- Steady stream: 1 load + 1 store per iteration, fully unrolled ----
#pragma unroll
  for (int i = 0; i < RB; ++i) {
    if (i + PF < NLOAD) raw[i + PF] = loadrow(r0 - 2 + i + PF);

    // vertical 5-max (pure VALU, no masking needed)
    float4 v = max4(max4(max4(raw[i], raw[i + 1]), max4(raw[i + 2], raw[i + 3])),
                    raw[i + 4]);
    if (!cvalid) v = ninf;        // OOB col lanes present -inf to neighbors

    // horizontal 5-max, channel stride 3; word c-2 only contributes .z/.w
    // and word c+2 only .x/.y -> 12 cross-lane b32 ops instead of 16.
    float4 Bv = shflup4(v, 1);
    float4 D  = shfldn4(v, 1);
    float Az = __shfl_up(v.z, 2);
    float Aw = __shfl_up(v.w, 2);
    float Ex = __shfl_down(v.x, 2);
    float Ey = __shfl_down(v.y, 2);
    float4 h;
    h.x = fmaxf(fmaxf(fmaxf(Az, Bv.y), fmaxf(v.x, v.w)), D.z);
    h.y = fmaxf(fmaxf(fmaxf(Aw, Bv.z), fmaxf(v.y, D.x)), D.w);
    h.z = fmaxf(fmaxf(fmaxf(Bv.x, Bv.w), fmaxf(v.z, D.y)), Ex);
    h.w = fmaxf(fmaxf(fmaxf(Bv.y, v.x), fmaxf(v.w, D.z)), Ey);

    if (willstore) {
      f32x4 hv; hv.x = h.x; hv.y = h.y; hv.z = h.z; hv.w = h.w;
      __builtin_nontemporal_store(
          hv, reinterpret_cast<f32x4*>(outb + (size_t)(r0 + i) * ROWBYTES + coff));
    }
  }
}

extern "C" void kernel_launch(void* const* d_in, const int* in_sizes, int n_in,
                              void* d_out, int out_size, void* d_ws, size_t ws_size,
                              hipStream_t stream) {
  const float* images = (const float*)d_in[0];
  float* out = (float*)d_out;
  dilate5_kernel<<<NBLK, 256, 0, stream>>>(images, out);
}

// Round 5
// 203.240 us; speedup vs baseline: 1.0128x; 1.0128x over previous
//
#include <hip/hip_runtime.h>

// Dilate = 5x5 per-channel max filter, SAME padding, (64,384,384,3) f32.
// v5b: inline-asm load pipeline — defeat the scheduler's load-sinking.
//   (v5 resubmit after infra failure; added early-clobber on asm load dest
//    so the 128-bit dest tuple can't alias the 64-bit address pair.)
//   v2-v4 post-mortem: VGPR 52/52/36 across launch_bounds, sched_barrier
//   fence, and explicit PF=8 streaming prove hipcc ALWAYS sinks plain loads
//   to first use -> ~1 load/wave in flight -> latency-bound at 2.4 TB/s
//   (8 KB/CU outstanding vs ~24 KB needed). Fix per HK/AITER pattern:
//   - all 16 row loads issued as volatile asm global_load_dwordx4
//     (cannot sink/reorder; 16 KB per wave genuinely in flight)
//   - counted s_waitcnt vmcnt(11-i) before consuming rows i..i+4, robust
//     to interleaved stores (FIFO accounting: completed >= i+5 loads)
//   - sched_barrier(0) around each waitcnt (rule #18: hipcc hoists reg-only
//     consumers past asm waitcnt otherwise)
//   Kept (counter-verified): XCD swizzle (FETCH 70->55 MB), address-clamp
//   vertical padding, vertical-first max, 12-op shuffle, nt stores.
//   grid = 64 img x 8 band-groups x 5 strips = 2560 blocks, 256 thr.

#define Bn 64
#define H 384
#define ROWBYTES 4608        // 384*3*4 bytes per image row
#define WF4 288              // float4s per row
#define RB 12                // output rows per wave
#define NLOAD (RB + 4)       // 16 input rows per wave (incl halo)
#define GROUPS 8             // 32 bands / 4 waves per block
#define STRIPS 5             // 5 * 60 = 300 >= 288 output f4 cols
#define SOUT 60
#define NBLK (Bn * GROUPS * STRIPS)   // 2560 (divisible by 8)
#define NEGINF (-3.402823466e+38f)

typedef float f32x4 __attribute__((ext_vector_type(4)));

template <int I> struct Ic { static constexpr int v = I; };
template <int I, int N, class F>
__device__ __forceinline__ void static_for(F f) {
  if constexpr (I < N) {
    f(Ic<I>{});
    static_for<I + 1, N>(f);
  }
}

// Volatile asm load: issued in program order, cannot be sunk by the
// scheduler. Result register is NOT ready until a matching vmcnt wait.
// "=&v" early-clobber: dest tuple must not alias the address pair
// (page-fault replay re-reads the address register).
__device__ __forceinline__ f32x4 gload4_async(const char* p) {
  f32x4 r;
  asm volatile("global_load_dwordx4 %0, %1, off" : "=&v"(r) : "v"(p));
  return r;
}

// Counted vmcnt wait, fenced both sides so (a) consumers cannot hoist
// above it, (b) prior ops cannot sink below it.
template <int N>
__device__ __forceinline__ void vm_wait() {
  __builtin_amdgcn_sched_barrier(0);
  asm volatile("s_waitcnt vmcnt(%0)" ::"n"(N) : "memory");
  __builtin_amdgcn_sched_barrier(0);
}

__device__ __forceinline__ f32x4 max4(f32x4 a, f32x4 b) {
  f32x4 r;
  r.x = fmaxf(a.x, b.x); r.y = fmaxf(a.y, b.y);
  r.z = fmaxf(a.z, b.z); r.w = fmaxf(a.w, b.w);
  return r;
}

__global__ __launch_bounds__(256, 4) void dilate5_kernel(
    const float* __restrict__ in, float* __restrict__ out) {
  const int wv = threadIdx.x >> 6;
  const int lane = threadIdx.x & 63;

  // XCD-aware swizzle: XCD x owns 8 consecutive images -> band-halo
  // re-reads hit its private L2 (verified: FETCH 70->55 MB).
  const int orig = blockIdx.x;
  int t = (orig & 7) * (NBLK / 8) + (orig >> 3);
  const int strip = t % STRIPS; t /= STRIPS;
  const int grp = t % GROUPS;   t /= GROUPS;
  const int b = t;

  const int row0 = (grp * 4 + wv) * RB;
  const int col = strip * SOUT - 2 + lane;          // owned f4 col (may be OOB)
  const bool cvalid = (col >= 0) && (col < WF4);
  const int ccl = col < 0 ? 0 : (col > WF4 - 1 ? WF4 - 1 : col);
  const size_t coff = (size_t)ccl * 16;
  const bool willstore = (lane >= 2) && (lane < 62) && (col < WF4);

  const char* __restrict__ imgb = (const char*)in + (size_t)b * H * ROWBYTES;
  char* __restrict__ outb = (char*)out + (size_t)b * H * ROWBYTES;

  // ---- Phase 1: issue ALL 16 row loads (volatile asm: they WILL issue
  // here, back-to-back; 16 KB in flight per wave). Vertical SAME padding
  // via address clamp (duplicated row is identity under max). ----
  f32x4 raw[NLOAD];
#pragma unroll
  for (int j = 0; j < NLOAD; ++j) {
    int gh = row0 - 2 + j;
    int ghc = gh < 0 ? 0 : (gh > H - 1 ? H - 1 : gh);
    raw[j] = gload4_async(imgb + (size_t)ghc * ROWBYTES + coff);
  }

  // ---- Phase 2: counted in-order drain; consume + store per row ----
  static_for<0, RB>([&](auto ic) {
    constexpr int i = decltype(ic)::v;
    // Need loads 0..i+4 complete. 16 loads issued first, s<=i stores after:
    // vmcnt(11-i) => completed >= (16+s)-(11-i) >= i+5. Robust + counted.
    vm_wait<(NLOAD - 1) - (i + 4)>();

    // vertical 5-max (pure VALU)
    f32x4 v = max4(max4(max4(raw[i], raw[i + 1]), max4(raw[i + 2], raw[i + 3])),
                   raw[i + 4]);
    if (!cvalid) { v.x = NEGINF; v.y = NEGINF; v.z = NEGINF; v.w = NEGINF; }

    // horizontal 5-max, channel stride 3: word c-2 contributes only .z/.w,
    // word c+2 only .x/.y -> 12 cross-lane b32 ops.
    float Bx = __shfl_up(v.x, 1), By = __shfl_up(v.y, 1);
    float Bz = __shfl_up(v.z, 1), Bw = __shfl_up(v.w, 1);
    float Dx = __shfl_down(v.x, 1), Dy = __shfl_down(v.y, 1);
    float Dz = __shfl_down(v.z, 1), Dw = __shfl_down(v.w, 1);
    float Az = __shfl_up(v.z, 2), Aw = __shfl_up(v.w, 2);
    float Ex = __shfl_down(v.x, 2), Ey = __shfl_down(v.y, 2);
    f32x4 h;
    h.x = fmaxf(fmaxf(fmaxf(Az, By), fmaxf(v.x, v.w)), Dz);
    h.y = fmaxf(fmaxf(fmaxf(Aw, Bz), fmaxf(v.y, Dx)), Dw);
    h.z = fmaxf(fmaxf(fmaxf(Bx, Bw), fmaxf(v.z, Dy)), Ex);
    h.w = fmaxf(fmaxf(fmaxf(By, v.x), fmaxf(v.w, Dz)), Ey);

    if (willstore)
      __builtin_nontemporal_store(
          h, reinterpret_cast<f32x4*>(outb + (size_t)(row0 + i) * ROWBYTES + coff));
  });
}

extern "C" void kernel_launch(void* const* d_in, const int* in_sizes, int n_in,
                              void* d_out, int out_size, void* d_ws, size_t ws_size,
                              hipStream_t stream) {
  const float* images = (const float*)d_in[0];
  float* out = (float*)d_out;
  dilate5_kernel<<<NBLK, 256, 0, stream>>>(images, out);
}